// Round 2
// baseline (225.873 us; speedup 1.0000x reference)
//
#include <hip/hip_runtime.h>
#include <hip/hip_bf16.h>

typedef __attribute__((ext_vector_type(8))) short short8;
typedef __attribute__((ext_vector_type(4))) float floatx4;

struct ushort4v { unsigned short x, y, z, w; };

static __device__ __forceinline__ unsigned short f2bf(float f) {
    __hip_bfloat16 h = __float2bfloat16(f);
    return *reinterpret_cast<unsigned short*>(&h);
}

#define ASYNC_COPY16(gsrc, ldst)                                                            \
    __builtin_amdgcn_global_load_lds((const __attribute__((address_space(1))) void*)(gsrc), \
                                     (__attribute__((address_space(3))) void*)(ldst), 16, 0, 0)

// ---------------------------------------------------------------------------
// mask encoding detection: jnp.bool_ may arrive as u8 (1B/elem) or i32.
// For i32 little-endian 0/1 values, all bytes at (i%4)!=0 within the first
// 8192 bytes are zero. For u8 random 0/1 data, essentially impossible.
// ---------------------------------------------------------------------------
__global__ void mask_detect(const unsigned char* __restrict__ m, int* __restrict__ flag) {
    __shared__ int s_or;
    if (threadIdx.x == 0) s_or = 0;
    __syncthreads();
    int acc = 0;
    for (int i = threadIdx.x; i < 8192; i += 256)
        if (i & 3) acc |= m[i];
    atomicOr(&s_or, acc);
    __syncthreads();
    if (threadIdx.x == 0) *flag = (s_or != 0) ? 1 : 0;  // 1 => u8 encoding
}

__global__ void mask_expand(const void* __restrict__ m, const int* __restrict__ flag,
                            float* __restrict__ maskadd, int n) {
    int i = blockIdx.x * 256 + threadIdx.x;
    if (i >= n) return;
    bool on;
    if (*flag)
        on = ((const unsigned char*)m)[i] != 0;
    else
        on = ((const int*)m)[i] != 0;
    maskadd[i] = on ? 0.0f : -1e9f;
}

// ---------------------------------------------------------------------------
// fp32 -> bf16 vectorized convert
// ---------------------------------------------------------------------------
__global__ __launch_bounds__(256) void convert_f32_bf16(const float* __restrict__ in,
                                                        unsigned short* __restrict__ out, long n4) {
    long i = (long)blockIdx.x * 256 + threadIdx.x;
    if (i >= n4) return;
    float4 v = ((const float4*)in)[i];
    ushort4v o;
    o.x = f2bf(v.x); o.y = f2bf(v.y); o.z = f2bf(v.z); o.w = f2bf(v.w);
    ((ushort4v*)out)[i] = o;
}

// ---------------------------------------------------------------------------
// weight transpose + convert: wT[z][j][i] = bf16(w_z[i][j]),  D=1024
// ---------------------------------------------------------------------------
__global__ void transpose_w_kernel(const float* __restrict__ w0, const float* __restrict__ w1,
                                   const float* __restrict__ w2, unsigned short* __restrict__ out) {
    __shared__ float t[32][33];
    const float* w = blockIdx.z == 0 ? w0 : (blockIdx.z == 1 ? w1 : w2);
    unsigned short* o = out + (long)blockIdx.z * 1024 * 1024;
    int c0 = blockIdx.x * 32, r0 = blockIdx.y * 32;
    for (int i = threadIdx.y; i < 32; i += 8)
        t[i][threadIdx.x] = w[(long)(r0 + i) * 1024 + c0 + threadIdx.x];
    __syncthreads();
    for (int i = threadIdx.y; i < 32; i += 8)
        o[(long)(c0 + i) * 1024 + r0 + threadIdx.x] = f2bf(t[threadIdx.x][i]);
}

// ---------------------------------------------------------------------------
// bf16 2D transpose (per z): out[z][c][r] = in[z][r][c]
// ---------------------------------------------------------------------------
__global__ void transpose_bf16(const unsigned short* __restrict__ in, unsigned short* __restrict__ out,
                               int rows, int cols, long sIn, long sOut) {
    __shared__ unsigned short t[32][34];
    const unsigned short* ib = in + (long)blockIdx.z * sIn;
    unsigned short* ob = out + (long)blockIdx.z * sOut;
    int c0 = blockIdx.x * 32, r0 = blockIdx.y * 32;
    for (int i = threadIdx.y; i < 32; i += 8)
        t[i][threadIdx.x] = ib[(long)(r0 + i) * cols + c0 + threadIdx.x];
    __syncthreads();
    for (int i = threadIdx.y; i < 32; i += 8)
        ob[(long)(c0 + i) * rows + r0 + threadIdx.x] = t[threadIdx.x][i];
}

// ---------------------------------------------------------------------------
// GEMM: C[M,N] = A[M,K] * BT[N,K]^T   (bf16 in, fp32 accum)
// m97 structure: 128x128 tile, BK=32, 4 waves (2x2), 16x16x32 MFMA,
// global_load_lds width=16 staging, linear LDS [row][k].
// EPI 0: bf16 store; EPI 1: fp32 store of acc*scale + maskadd[row] (scores);
// EPI 2: fp32 store.
// ---------------------------------------------------------------------------
template <int EPI>
__global__ __launch_bounds__(256, 2) void gemm_bt(const unsigned short* __restrict__ A,
                                                  const unsigned short* __restrict__ B,
                                                  void* __restrict__ Cv,
                                                  const float* __restrict__ maskadd,
                                                  int K, int lda, int ldb, int ldc,
                                                  long sA, long sB, long sC, long sMask,
                                                  float scale) {
    __shared__ unsigned short lA[128 * 32];
    __shared__ unsigned short lB[128 * 32];
    const int tid = threadIdx.x;
    const int wave = tid >> 6, lane = tid & 63;
    const int wr = wave >> 1, wc = wave & 1;
    const long m0 = (long)blockIdx.x * 128;
    const long n0 = (long)blockIdx.y * 128;
    const unsigned short* Ab = A + (long)blockIdx.z * sA + m0 * lda;
    const unsigned short* Bb = B + (long)blockIdx.z * sB + n0 * ldb;
    const int srow = tid >> 2;          // 0..63
    const int scol = (tid & 3) * 8;     // 0,8,16,24

    floatx4 acc[4][4] = {};

    const int fr = lane & 15;
    const int fk = (lane >> 4) * 8;

    for (int kb = 0; kb < K; kb += 32) {
        ASYNC_COPY16(Ab + (long)srow * lda + kb + scol,        &lA[srow * 32 + scol]);
        ASYNC_COPY16(Ab + (long)(64 + srow) * lda + kb + scol, &lA[(64 + srow) * 32 + scol]);
        ASYNC_COPY16(Bb + (long)srow * ldb + kb + scol,        &lB[srow * 32 + scol]);
        ASYNC_COPY16(Bb + (long)(64 + srow) * ldb + kb + scol, &lB[(64 + srow) * 32 + scol]);
        __syncthreads();

        short8 af[4], bfr[4];
#pragma unroll
        for (int mi = 0; mi < 4; mi++)
            af[mi] = *(const short8*)&lA[(wr * 64 + mi * 16 + fr) * 32 + fk];
#pragma unroll
        for (int ni = 0; ni < 4; ni++)
            bfr[ni] = *(const short8*)&lB[(wc * 64 + ni * 16 + fr) * 32 + fk];
#pragma unroll
        for (int mi = 0; mi < 4; mi++)
#pragma unroll
            for (int ni = 0; ni < 4; ni++)
                acc[mi][ni] = __builtin_amdgcn_mfma_f32_16x16x32_bf16(af[mi], bfr[ni], acc[mi][ni], 0, 0, 0);
        __syncthreads();
    }

    const int crow = (lane >> 4) * 4;
    const int ccol = lane & 15;
#pragma unroll
    for (int mi = 0; mi < 4; mi++) {
#pragma unroll
        for (int ni = 0; ni < 4; ni++) {
#pragma unroll
            for (int j = 0; j < 4; j++) {
                long r = m0 + wr * 64 + mi * 16 + crow + j;
                long c = n0 + wc * 64 + ni * 16 + ccol;
                float v = acc[mi][ni][j];
                if (EPI == 0) {
                    ((unsigned short*)Cv)[(long)blockIdx.z * sC + r * ldc + c] = f2bf(v);
                } else if (EPI == 1) {
                    float sv = v * scale;
                    sv = sv + maskadd[(long)blockIdx.z * sMask + r];  // fp32 add: collapses to -1e9 for masked rows, like the reference
                    ((float*)Cv)[(long)blockIdx.z * sC + r * ldc + c] = sv;
                } else {
                    ((float*)Cv)[(long)blockIdx.z * sC + r * ldc + c] = v;
                }
            }
        }
    }
}

// ---------------------------------------------------------------------------
// row softmax: 2048 fp32 -> 2048 bf16, one block (256 thr) per row
// ---------------------------------------------------------------------------
__global__ __launch_bounds__(256) void softmax_rows(const float* __restrict__ S,
                                                    unsigned short* __restrict__ P,
                                                    long strideS, long strideP) {
    const int tid = threadIdx.x;
    const long row = blockIdx.x;
    const float4* src = (const float4*)(S + row * strideS);
    float4 a = src[tid];
    float4 b = src[tid + 256];

    float m = fmaxf(fmaxf(fmaxf(a.x, a.y), fmaxf(a.z, a.w)),
                    fmaxf(fmaxf(b.x, b.y), fmaxf(b.z, b.w)));
#pragma unroll
    for (int i = 1; i < 64; i <<= 1) m = fmaxf(m, __shfl_xor(m, i));
    __shared__ float sm[4];
    __shared__ float ss[4];
    if ((tid & 63) == 0) sm[tid >> 6] = m;
    __syncthreads();
    m = fmaxf(fmaxf(sm[0], sm[1]), fmaxf(sm[2], sm[3]));

    float e[8];
    e[0] = expf(a.x - m); e[1] = expf(a.y - m); e[2] = expf(a.z - m); e[3] = expf(a.w - m);
    e[4] = expf(b.x - m); e[5] = expf(b.y - m); e[6] = expf(b.z - m); e[7] = expf(b.w - m);
    float s = ((e[0] + e[1]) + (e[2] + e[3])) + ((e[4] + e[5]) + (e[6] + e[7]));
#pragma unroll
    for (int i = 1; i < 64; i <<= 1) s += __shfl_xor(s, i);
    if ((tid & 63) == 0) ss[tid >> 6] = s;
    __syncthreads();
    s = (ss[0] + ss[1]) + (ss[2] + ss[3]);
    float inv = 1.0f / s;

    unsigned short* dst = P + row * strideP;
    ushort4v o0, o1;
    o0.x = f2bf(e[0] * inv); o0.y = f2bf(e[1] * inv); o0.z = f2bf(e[2] * inv); o0.w = f2bf(e[3] * inv);
    o1.x = f2bf(e[4] * inv); o1.y = f2bf(e[5] * inv); o1.z = f2bf(e[6] * inv); o1.w = f2bf(e[7] * inv);
    ((ushort4v*)dst)[tid] = o0;
    ((ushort4v*)dst)[tid + 256] = o1;
}

// ---------------------------------------------------------------------------
extern "C" void kernel_launch(void* const* d_in, const int* in_sizes, int n_in,
                              void* d_out, int out_size, void* d_ws, size_t ws_size,
                              hipStream_t stream) {
    const float* x  = (const float*)d_in[0];
    const void*  mask = d_in[1];
    const float* qw = (const float*)d_in[2];
    const float* kw = (const float*)d_in[3];
    const float* vw = (const float*)d_in[4];
    float* out = (float*)d_out;

    constexpr int B = 4, S = 2048, D = 1024;
    constexpr long BS  = (long)B * S;      // 8192
    constexpr long BSD = BS * D;           // 8388608

    char* w = (char*)d_ws;
    auto alloc = [&](size_t bytes) {
        char* p = w;
        w += (bytes + 255) & ~(size_t)255;
        return p;
    };
    int*            flag    = (int*)alloc(256);
    float*          maskadd = (float*)alloc(BS * 4);
    unsigned short* xb      = (unsigned short*)alloc((size_t)BSD * 2);
    unsigned short* wT      = (unsigned short*)alloc((size_t)3 * D * D * 2);
    unsigned short* qkv     = (unsigned short*)alloc((size_t)3 * BSD * 2);
    unsigned short* Qb = qkv;
    unsigned short* Kb = qkv + BSD;
    unsigned short* Vb = qkv + 2 * BSD;
    unsigned short* Vt      = (unsigned short*)alloc((size_t)BSD * 2);

    size_t base_used = (size_t)(w - (char*)d_ws);
    size_t scoresB = (size_t)B * S * S * 4;  // 64 MiB
    size_t pB      = (size_t)B * S * S * 2;  // 32 MiB
    bool batched = ws_size >= base_used + scoresB + pB + 1024;

    float* scores;
    unsigned short* P;
    if (batched) {
        scores = (float*)alloc(scoresB);
        P      = (unsigned short*)alloc(pB);
    } else {
        scores = (float*)alloc((size_t)S * S * 4);
        P      = (unsigned short*)alloc((size_t)S * S * 2);
    }

    const float scale = 0.03125f;  // 1/sqrt(1024), exact

    mask_detect<<<1, 256, 0, stream>>>((const unsigned char*)mask, flag);
    mask_expand<<<(int)(BS / 256), 256, 0, stream>>>(mask, flag, maskadd, (int)BS);
    convert_f32_bf16<<<(int)(BSD / 1024), 256, 0, stream>>>(x, xb, BSD / 4);
    transpose_w_kernel<<<dim3(32, 32, 3), dim3(32, 8), 0, stream>>>(qw, kw, vw, wT);

    // Q,K,V projections: M=8192, N=1024, K=1024; grid.z selects weight/output
    gemm_bt<0><<<dim3(64, 8, 3), 256, 0, stream>>>(xb, wT, qkv, nullptr,
                                                   1024, 1024, 1024, 1024,
                                                   0L, (long)D * D, BSD, 0L, 1.0f);

    // V transpose: Vt[b][d][s]
    transpose_bf16<<<dim3(D / 32, S / 32, B), dim3(32, 8), 0, stream>>>(Vb, Vt, S, D,
                                                                        (long)S * D, (long)S * D);

    if (batched) {
        gemm_bt<1><<<dim3(16, 16, B), 256, 0, stream>>>(Qb, Kb, scores, maskadd,
                                                        1024, 1024, 1024, 2048,
                                                        (long)S * D, (long)S * D, (long)S * S, (long)S, scale);
        softmax_rows<<<(int)BS, 256, 0, stream>>>(scores, P, 2048, 2048);
        gemm_bt<2><<<dim3(16, 8, B), 256, 0, stream>>>(P, Vt, out, nullptr,
                                                       2048, 2048, 2048, 1024,
                                                       (long)S * S, (long)D * S, (long)S * D, 0L, 1.0f);
    } else {
        for (int b = 0; b < B; b++) {
            gemm_bt<1><<<dim3(16, 16, 1), 256, 0, stream>>>(Qb + (long)b * S * D, Kb + (long)b * S * D,
                                                            scores, maskadd + (long)b * S,
                                                            1024, 1024, 1024, 2048,
                                                            0L, 0L, 0L, 0L, scale);
            softmax_rows<<<S, 256, 0, stream>>>(scores, P, 2048, 2048);
            gemm_bt<2><<<dim3(16, 8, 1), 256, 0, stream>>>(P, Vt + (long)b * D * S, out + (long)b * S * D,
                                                           nullptr,
                                                           2048, 2048, 2048, 1024,
                                                           0L, 0L, 0L, 0L, 1.0f);
        }
    }
}

// Round 3
// 207.713 us; speedup vs baseline: 1.0874x; 1.0874x over previous
//
#include <hip/hip_runtime.h>
#include <hip/hip_bf16.h>

typedef __attribute__((ext_vector_type(8))) short short8;
typedef __attribute__((ext_vector_type(4))) float floatx4;

struct ushort4v { unsigned short x, y, z, w; };

static __device__ __forceinline__ unsigned short f2bf(float f) {
    __hip_bfloat16 h = __float2bfloat16(f);
    return *reinterpret_cast<unsigned short*>(&h);
}

static __device__ __forceinline__ float bf2f(unsigned short u) {
    unsigned int v = ((unsigned int)u) << 16;
    return *reinterpret_cast<float*>(&v);
}

#define ASYNC_COPY16(gsrc, ldst)                                                            \
    __builtin_amdgcn_global_load_lds((const __attribute__((address_space(1))) void*)(gsrc), \
                                     (__attribute__((address_space(3))) void*)(ldst), 16, 0, 0)

// ---------------------------------------------------------------------------
// mask encoding detection: jnp.bool_ may arrive as u8 (1B/elem) or i32.
// ---------------------------------------------------------------------------
__global__ void mask_detect(const unsigned char* __restrict__ m, int* __restrict__ flag) {
    __shared__ int s_or;
    if (threadIdx.x == 0) s_or = 0;
    __syncthreads();
    int acc = 0;
    for (int i = threadIdx.x; i < 8192; i += 256)
        if (i & 3) acc |= m[i];
    atomicOr(&s_or, acc);
    __syncthreads();
    if (threadIdx.x == 0) *flag = (s_or != 0) ? 1 : 0;  // 1 => u8 encoding
}

// keep[i] = 1.0f if attended (mask true), 0.0f if masked-out query row.
// In the scores epilogue we compute exp(score * keep): keep=0 -> exp(0)=1 for
// the whole row -> exactly-uniform softmax, identical to the reference where
// score*(1/32) + (-1e9) rounds to exactly -1e9 for every entry.
__global__ void mask_expand(const void* __restrict__ m, const int* __restrict__ flag,
                            float* __restrict__ keep, int n) {
    int i = blockIdx.x * 256 + threadIdx.x;
    if (i >= n) return;
    bool on;
    if (*flag)
        on = ((const unsigned char*)m)[i] != 0;
    else
        on = ((const int*)m)[i] != 0;
    keep[i] = on ? 1.0f : 0.0f;
}

// ---------------------------------------------------------------------------
// fp32 -> bf16 vectorized convert
// ---------------------------------------------------------------------------
__global__ __launch_bounds__(256) void convert_f32_bf16(const float* __restrict__ in,
                                                        unsigned short* __restrict__ out, long n4) {
    long i = (long)blockIdx.x * 256 + threadIdx.x;
    if (i >= n4) return;
    float4 v = ((const float4*)in)[i];
    ushort4v o;
    o.x = f2bf(v.x); o.y = f2bf(v.y); o.z = f2bf(v.z); o.w = f2bf(v.w);
    ((ushort4v*)out)[i] = o;
}

// ---------------------------------------------------------------------------
// weight transpose + convert: wT[z][j][i] = bf16(w_z[i][j]),  D=1024
// ---------------------------------------------------------------------------
__global__ void transpose_w_kernel(const float* __restrict__ w0, const float* __restrict__ w1,
                                   const float* __restrict__ w2, unsigned short* __restrict__ out) {
    __shared__ float t[32][33];
    const float* w = blockIdx.z == 0 ? w0 : (blockIdx.z == 1 ? w1 : w2);
    unsigned short* o = out + (long)blockIdx.z * 1024 * 1024;
    int c0 = blockIdx.x * 32, r0 = blockIdx.y * 32;
    for (int i = threadIdx.y; i < 32; i += 8)
        t[i][threadIdx.x] = w[(long)(r0 + i) * 1024 + c0 + threadIdx.x];
    __syncthreads();
    for (int i = threadIdx.y; i < 32; i += 8)
        o[(long)(c0 + i) * 1024 + r0 + threadIdx.x] = f2bf(t[threadIdx.x][i]);
}

// ---------------------------------------------------------------------------
// bf16 2D transpose (per z): out[z][c][r] = in[z][r][c]
// ---------------------------------------------------------------------------
__global__ void transpose_bf16(const unsigned short* __restrict__ in, unsigned short* __restrict__ out,
                               int rows, int cols, long sIn, long sOut) {
    __shared__ unsigned short t[32][34];
    const unsigned short* ib = in + (long)blockIdx.z * sIn;
    unsigned short* ob = out + (long)blockIdx.z * sOut;
    int c0 = blockIdx.x * 32, r0 = blockIdx.y * 32;
    for (int i = threadIdx.y; i < 32; i += 8)
        t[i][threadIdx.x] = ib[(long)(r0 + i) * cols + c0 + threadIdx.x];
    __syncthreads();
    for (int i = threadIdx.y; i < 32; i += 8)
        ob[(long)(c0 + i) * rows + r0 + threadIdx.x] = t[threadIdx.x][i];
}

// ---------------------------------------------------------------------------
// GEMM body: C[M,N] = A[M,K] * BT[N,K]^T   (bf16 in, fp32 accum)
// m97 structure: 128x128 tile, BK=32, 4 waves (2x2), 16x16x32 MFMA,
// global_load_lds width=16 staging, linear LDS [row][k].
// EPI 0: bf16 store (QKV projection)
// EPI 1: bf16 store of exp(acc*scale*keep[row])   (unnormalized P)
// EPI 2: fp32 store of acc * invsum[row]          (PV with fused normalize)
// ---------------------------------------------------------------------------
template <int EPI>
static __device__ __forceinline__ void gemm_body(const unsigned short* __restrict__ A,
                                                 const unsigned short* __restrict__ B,
                                                 void* __restrict__ Cv,
                                                 const float* __restrict__ aux,
                                                 int K, int lda, int ldb, int ldc,
                                                 long sA, long sB, long sC, long sAux,
                                                 float scale) {
    __shared__ unsigned short lA[128 * 32];
    __shared__ unsigned short lB[128 * 32];
    const int tid = threadIdx.x;
    const int wave = tid >> 6, lane = tid & 63;
    const int wr = wave >> 1, wc = wave & 1;
    const long m0 = (long)blockIdx.x * 128;
    const long n0 = (long)blockIdx.y * 128;
    const unsigned short* Ab = A + (long)blockIdx.z * sA + m0 * lda;
    const unsigned short* Bb = B + (long)blockIdx.z * sB + n0 * ldb;
    const int srow = tid >> 2;          // 0..63
    const int scol = (tid & 3) * 8;     // 0,8,16,24

    floatx4 acc[4][4] = {};

    const int fr = lane & 15;
    const int fk = (lane >> 4) * 8;

    for (int kb = 0; kb < K; kb += 32) {
        ASYNC_COPY16(Ab + (long)srow * lda + kb + scol,        &lA[srow * 32 + scol]);
        ASYNC_COPY16(Ab + (long)(64 + srow) * lda + kb + scol, &lA[(64 + srow) * 32 + scol]);
        ASYNC_COPY16(Bb + (long)srow * ldb + kb + scol,        &lB[srow * 32 + scol]);
        ASYNC_COPY16(Bb + (long)(64 + srow) * ldb + kb + scol, &lB[(64 + srow) * 32 + scol]);
        __syncthreads();

        short8 af[4], bfr[4];
#pragma unroll
        for (int mi = 0; mi < 4; mi++)
            af[mi] = *(const short8*)&lA[(wr * 64 + mi * 16 + fr) * 32 + fk];
#pragma unroll
        for (int ni = 0; ni < 4; ni++)
            bfr[ni] = *(const short8*)&lB[(wc * 64 + ni * 16 + fr) * 32 + fk];
#pragma unroll
        for (int mi = 0; mi < 4; mi++)
#pragma unroll
            for (int ni = 0; ni < 4; ni++)
                acc[mi][ni] = __builtin_amdgcn_mfma_f32_16x16x32_bf16(af[mi], bfr[ni], acc[mi][ni], 0, 0, 0);
        __syncthreads();
    }

    const int crow = (lane >> 4) * 4;
    const int ccol = lane & 15;
#pragma unroll
    for (int mi = 0; mi < 4; mi++) {
#pragma unroll
        for (int j = 0; j < 4; j++) {
            long r = m0 + wr * 64 + mi * 16 + crow + j;
            float rowf = 0.0f;
            if (EPI == 1) rowf = scale * aux[(long)blockIdx.z * sAux + r];   // scale*keep
            if (EPI == 2) rowf = aux[(long)blockIdx.z * sAux + r];           // invsum
#pragma unroll
            for (int ni = 0; ni < 4; ni++) {
                long c = n0 + wc * 64 + ni * 16 + ccol;
                float v = acc[mi][ni][j];
                if (EPI == 0) {
                    ((unsigned short*)Cv)[(long)blockIdx.z * sC + r * ldc + c] = f2bf(v);
                } else if (EPI == 1) {
                    ((unsigned short*)Cv)[(long)blockIdx.z * sC + r * ldc + c] = f2bf(__expf(v * rowf));
                } else {
                    ((float*)Cv)[(long)blockIdx.z * sC + r * ldc + c] = v * rowf;
                }
            }
        }
    }
}

// Distinct kernel names so rocprof rows are distinguishable per GEMM stage.
__global__ __launch_bounds__(256, 2) void gemm_qkv(const unsigned short* __restrict__ A,
                                                   const unsigned short* __restrict__ B,
                                                   void* __restrict__ Cv,
                                                   int K, int lda, int ldb, int ldc,
                                                   long sA, long sB, long sC) {
    gemm_body<0>(A, B, Cv, nullptr, K, lda, ldb, ldc, sA, sB, sC, 0L, 1.0f);
}

__global__ __launch_bounds__(256, 2) void gemm_scores(const unsigned short* __restrict__ A,
                                                      const unsigned short* __restrict__ B,
                                                      void* __restrict__ Cv,
                                                      const float* __restrict__ keep,
                                                      int K, int lda, int ldb, int ldc,
                                                      long sA, long sB, long sC, long sAux,
                                                      float scale) {
    gemm_body<1>(A, B, Cv, keep, K, lda, ldb, ldc, sA, sB, sC, sAux, scale);
}

__global__ __launch_bounds__(256, 2) void gemm_pv(const unsigned short* __restrict__ A,
                                                  const unsigned short* __restrict__ B,
                                                  void* __restrict__ Cv,
                                                  const float* __restrict__ invsum,
                                                  int K, int lda, int ldb, int ldc,
                                                  long sA, long sB, long sC, long sAux) {
    gemm_body<2>(A, B, Cv, invsum, K, lda, ldb, ldc, sA, sB, sC, sAux, 1.0f);
}

// ---------------------------------------------------------------------------
// row sum of unnormalized bf16 P -> inverse sum (fp32), one block per row.
// Deterministic fixed-order tree reduction (no atomics).
// ---------------------------------------------------------------------------
__global__ __launch_bounds__(256) void rowsum_inv(const unsigned short* __restrict__ P,
                                                  float* __restrict__ inv, long strideP) {
    const int tid = threadIdx.x;
    const long row = blockIdx.x;
    short8 v = ((const short8*)(P + row * strideP))[tid];
    float s = 0.0f;
#pragma unroll
    for (int i = 0; i < 8; i++) s += bf2f((unsigned short)v[i]);
#pragma unroll
    for (int i = 1; i < 64; i <<= 1) s += __shfl_xor(s, i);
    __shared__ float ss[4];
    if ((tid & 63) == 0) ss[tid >> 6] = s;
    __syncthreads();
    if (tid == 0) {
        float t = (ss[0] + ss[1]) + (ss[2] + ss[3]);
        inv[row] = 1.0f / t;
    }
}

// ---------------------------------------------------------------------------
extern "C" void kernel_launch(void* const* d_in, const int* in_sizes, int n_in,
                              void* d_out, int out_size, void* d_ws, size_t ws_size,
                              hipStream_t stream) {
    const float* x  = (const float*)d_in[0];
    const void*  mask = d_in[1];
    const float* qw = (const float*)d_in[2];
    const float* kw = (const float*)d_in[3];
    const float* vw = (const float*)d_in[4];
    float* out = (float*)d_out;

    constexpr int B = 4, S = 2048, D = 1024;
    constexpr long BS  = (long)B * S;      // 8192
    constexpr long BSD = BS * D;           // 8388608

    char* w = (char*)d_ws;
    auto alloc = [&](size_t bytes) {
        char* p = w;
        w += (bytes + 255) & ~(size_t)255;
        return p;
    };
    int*            flag    = (int*)alloc(256);
    float*          keep    = (float*)alloc(BS * 4);
    float*          invsum  = (float*)alloc(BS * 4);
    unsigned short* xb      = (unsigned short*)alloc((size_t)BSD * 2);
    unsigned short* wT      = (unsigned short*)alloc((size_t)3 * D * D * 2);
    unsigned short* qkv     = (unsigned short*)alloc((size_t)3 * BSD * 2);
    unsigned short* Qb = qkv;
    unsigned short* Kb = qkv + BSD;
    unsigned short* Vb = qkv + 2 * BSD;
    unsigned short* Vt      = (unsigned short*)alloc((size_t)BSD * 2);

    size_t base_used = (size_t)(w - (char*)d_ws);
    size_t pB = (size_t)B * S * S * 2;  // 32 MiB unnormalized P (bf16)
    bool batched = ws_size >= base_used + pB + 1024;

    unsigned short* P;
    if (batched) {
        P = (unsigned short*)alloc(pB);
    } else {
        P = (unsigned short*)alloc((size_t)S * S * 2);
    }

    const float scale = 0.03125f;  // 1/sqrt(1024), exact

    mask_detect<<<1, 256, 0, stream>>>((const unsigned char*)mask, flag);
    mask_expand<<<(int)(BS / 256), 256, 0, stream>>>(mask, flag, keep, (int)BS);
    convert_f32_bf16<<<(int)(BSD / 1024), 256, 0, stream>>>(x, xb, BSD / 4);
    transpose_w_kernel<<<dim3(32, 32, 3), dim3(32, 8), 0, stream>>>(qw, kw, vw, wT);

    // Q,K,V projections: M=8192, N=1024, K=1024; grid.z selects weight/output
    gemm_qkv<<<dim3(64, 8, 3), 256, 0, stream>>>(xb, wT, qkv,
                                                 1024, 1024, 1024, 1024,
                                                 0L, (long)D * D, BSD);

    // V transpose: Vt[b][d][s]
    transpose_bf16<<<dim3(D / 32, S / 32, B), dim3(32, 8), 0, stream>>>(Vb, Vt, S, D,
                                                                        (long)S * D, (long)S * D);

    if (batched) {
        // P = exp(QK^T * scale * keep) unnormalized, bf16
        gemm_scores<<<dim3(16, 16, B), 256, 0, stream>>>(Qb, Kb, P, keep,
                                                         1024, 1024, 1024, 2048,
                                                         (long)S * D, (long)S * D, (long)S * S, (long)S, scale);
        rowsum_inv<<<(int)BS, 256, 0, stream>>>(P, invsum, 2048);
        // out = (P * invsum[row]) . V
        gemm_pv<<<dim3(16, 8, B), 256, 0, stream>>>(P, Vt, out, invsum,
                                                    2048, 2048, 2048, 1024,
                                                    (long)S * S, (long)D * S, (long)S * D, (long)S);
    } else {
        for (int b = 0; b < B; b++) {
            gemm_scores<<<dim3(16, 16, 1), 256, 0, stream>>>(Qb + (long)b * S * D, Kb + (long)b * S * D,
                                                             P, keep + (long)b * S,
                                                             1024, 1024, 1024, 2048,
                                                             0L, 0L, 0L, 0L, scale);
            rowsum_inv<<<S, 256, 0, stream>>>(P, invsum + (long)b * S, 2048);
            gemm_pv<<<dim3(16, 8, 1), 256, 0, stream>>>(P, Vt + (long)b * D * S, out + (long)b * S * D,
                                                        invsum + (long)b * S,
                                                        2048, 2048, 2048, 1024,
                                                        0L, 0L, 0L, 0L);
        }
    }
}

// Round 4
// 198.349 us; speedup vs baseline: 1.1388x; 1.0472x over previous
//
#include <hip/hip_runtime.h>
#include <hip/hip_bf16.h>

typedef __attribute__((ext_vector_type(8))) short short8;
typedef __attribute__((ext_vector_type(4))) float floatx4;

struct ushort4v { unsigned short x, y, z, w; };

static __device__ __forceinline__ unsigned short f2bf(float f) {
    __hip_bfloat16 h = __float2bfloat16(f);
    return *reinterpret_cast<unsigned short*>(&h);
}

static __device__ __forceinline__ float bf2f(unsigned short u) {
    unsigned int v = ((unsigned int)u) << 16;
    return *reinterpret_cast<float*>(&v);
}

#define ASYNC_COPY16(gsrc, ldst)                                                            \
    __builtin_amdgcn_global_load_lds((const __attribute__((address_space(1))) void*)(gsrc), \
                                     (__attribute__((address_space(3))) void*)(ldst), 16, 0, 0)

// raw barrier with compiler memory fence on both sides: LDS reads/writes and
// global_load_lds must not be moved across it (rule #18/#21 discipline).
static __device__ __forceinline__ void block_barrier() {
    asm volatile("" ::: "memory");
    __builtin_amdgcn_s_barrier();
    asm volatile("" ::: "memory");
}

// ---------------------------------------------------------------------------
// mask encoding detection: jnp.bool_ may arrive as u8 (1B/elem) or i32.
// ---------------------------------------------------------------------------
__global__ void mask_detect(const unsigned char* __restrict__ m, int* __restrict__ flag) {
    __shared__ int s_or;
    if (threadIdx.x == 0) s_or = 0;
    __syncthreads();
    int acc = 0;
    for (int i = threadIdx.x; i < 8192; i += 256)
        if (i & 3) acc |= m[i];
    atomicOr(&s_or, acc);
    __syncthreads();
    if (threadIdx.x == 0) *flag = (s_or != 0) ? 1 : 0;  // 1 => u8 encoding
}

// keep[i] = 1.0f if attended, 0.0f if masked query row. exp(score*0)=1 for the
// whole row -> exactly-uniform softmax, identical to the reference where
// score*(1/32) + (-1e9) rounds to exactly -1e9 in fp32.
__global__ void mask_expand(const void* __restrict__ m, const int* __restrict__ flag,
                            float* __restrict__ keep, int n) {
    int i = blockIdx.x * 256 + threadIdx.x;
    if (i >= n) return;
    bool on;
    if (*flag)
        on = ((const unsigned char*)m)[i] != 0;
    else
        on = ((const int*)m)[i] != 0;
    keep[i] = on ? 1.0f : 0.0f;
}

// ---------------------------------------------------------------------------
__global__ __launch_bounds__(256) void convert_f32_bf16(const float* __restrict__ in,
                                                        unsigned short* __restrict__ out, long n4) {
    long i = (long)blockIdx.x * 256 + threadIdx.x;
    if (i >= n4) return;
    float4 v = ((const float4*)in)[i];
    ushort4v o;
    o.x = f2bf(v.x); o.y = f2bf(v.y); o.z = f2bf(v.z); o.w = f2bf(v.w);
    ((ushort4v*)out)[i] = o;
}

// ---------------------------------------------------------------------------
__global__ void transpose_w_kernel(const float* __restrict__ w0, const float* __restrict__ w1,
                                   const float* __restrict__ w2, unsigned short* __restrict__ out) {
    __shared__ float t[32][33];
    const float* w = blockIdx.z == 0 ? w0 : (blockIdx.z == 1 ? w1 : w2);
    unsigned short* o = out + (long)blockIdx.z * 1024 * 1024;
    int c0 = blockIdx.x * 32, r0 = blockIdx.y * 32;
    for (int i = threadIdx.y; i < 32; i += 8)
        t[i][threadIdx.x] = w[(long)(r0 + i) * 1024 + c0 + threadIdx.x];
    __syncthreads();
    for (int i = threadIdx.y; i < 32; i += 8)
        o[(long)(c0 + i) * 1024 + r0 + threadIdx.x] = f2bf(t[threadIdx.x][i]);
}

// ---------------------------------------------------------------------------
__global__ void transpose_bf16(const unsigned short* __restrict__ in, unsigned short* __restrict__ out,
                               int rows, int cols, long sIn, long sOut) {
    __shared__ unsigned short t[32][34];
    const unsigned short* ib = in + (long)blockIdx.z * sIn;
    unsigned short* ob = out + (long)blockIdx.z * sOut;
    int c0 = blockIdx.x * 32, r0 = blockIdx.y * 32;
    for (int i = threadIdx.y; i < 32; i += 8)
        t[i][threadIdx.x] = ib[(long)(r0 + i) * cols + c0 + threadIdx.x];
    __syncthreads();
    for (int i = threadIdx.y; i < 32; i += 8)
        ob[(long)(c0 + i) * rows + r0 + threadIdx.x] = t[threadIdx.x][i];
}

// ---------------------------------------------------------------------------
// Deep-pipelined GEMM: C[M,N] = A[M,K] * BT[N,K]^T  (bf16 in, fp32 accum)
// BM x 256 tile, BK=64, 8 waves (2M x 4N), per-wave (BM/2) x 64 output.
// Depth-2 double-buffer: tile t+2 staged after the barrier ending reads of
// buf[t&1]; counted s_waitcnt vmcnt(L) (never 0 in steady state) + barrier
// before consuming. LDS XOR-swizzle (bit6 ^= row-bit2, involution) applied to
// BOTH the pre-swizzled global source (global_load_lds writes linearly) and
// the ds_read address -> fragment reads spread over all 32 banks.
// EPI 0: bf16 C; EPI 1: bf16 exp(acc*scale*keep[row]); EPI 2: fp32 acc*inv[row].
// ---------------------------------------------------------------------------
template <int EPI, int BM>
static __device__ __forceinline__ void gemm8_body(const unsigned short* __restrict__ A,
                                                  const unsigned short* __restrict__ B,
                                                  void* __restrict__ Cv,
                                                  const float* __restrict__ aux,
                                                  int K, int lda, int ldb, int ldc,
                                                  long sA, long sB, long sC, long sAux,
                                                  float scale) {
    constexpr int M_REP = BM / 32;          // 8 (BM=256) or 4 (BM=128)
    constexpr int LA    = BM * 128 / 8192;  // A-tile loads per thread
    constexpr int LB    = 4;                // B-tile loads per thread
    constexpr int TILE  = (BM + 256) * 128; // bytes per K-tile buffer (A+B)
    __shared__ char sm[2 * TILE];

    const int tid = threadIdx.x;
    const int wid = tid >> 6, lane = tid & 63;
    const int wm  = wid >> 2, wn = wid & 3;       // 2 x 4 wave grid
    const int fr  = lane & 15, fk = lane >> 4;    // fragment row / 16B col unit
    const long m0 = (long)blockIdx.x * BM;
    const long n0 = (long)blockIdx.y * 256;
    const unsigned short* Ab = A + (long)blockIdx.z * sA + m0 * lda;
    const unsigned short* Bb = B + (long)blockIdx.z * sB + n0 * ldb;
    const int NT = K >> 6;

    floatx4 acc[M_REP][4] = {};

    auto stage = [&](int kt) {
        char* dA = sm + (kt & 1) * TILE;
        char* dB = dA + BM * 128;
        const int kb = kt << 6;
#pragma unroll
        for (int i = 0; i < LA; i++) {
            int lam = i * 8192 + tid * 16;                  // linear LDS byte
            int lg  = lam ^ (((lam >> 9) & 1) << 6);        // pre-swizzled logical
            ASYNC_COPY16(Ab + (long)(lg >> 7) * lda + kb + ((lg & 127) >> 1), dA + lam);
        }
#pragma unroll
        for (int i = 0; i < LB; i++) {
            int lam = i * 8192 + tid * 16;
            int lg  = lam ^ (((lam >> 9) & 1) << 6);
            ASYNC_COPY16(Bb + (long)(lg >> 7) * ldb + kb + ((lg & 127) >> 1), dB + lam);
        }
    };

    stage(0);
    stage(1);

    for (int t = 0; t < NT; t++) {
        // wait for tile t's loads (L = LA+LB per tile; 2 tiles in flight)
        if (t + 1 < NT) {
            if constexpr (BM == 256) asm volatile("s_waitcnt vmcnt(8)" ::: "memory");
            else                     asm volatile("s_waitcnt vmcnt(6)" ::: "memory");
        } else {
            asm volatile("s_waitcnt vmcnt(0)" ::: "memory");
        }
        block_barrier();                       // all waves' tile-t data resident

        const char* bA = sm + (t & 1) * TILE;
        const char* bB = bA + BM * 128;
#pragma unroll
        for (int ks = 0; ks < 2; ks++) {
            short8 af[M_REP], bf[4];
#pragma unroll
            for (int mi = 0; mi < M_REP; mi++) {
                int row = wm * (BM / 2) + mi * 16 + fr;
                int c   = (ks * 64 + fk * 16) ^ ((row & 4) << 4);
                af[mi] = *(const short8*)(bA + row * 128 + c);
            }
#pragma unroll
            for (int ni = 0; ni < 4; ni++) {
                int row = wn * 64 + ni * 16 + fr;
                int c   = (ks * 64 + fk * 16) ^ ((row & 4) << 4);
                bf[ni] = *(const short8*)(bB + row * 128 + c);
            }
            __builtin_amdgcn_s_setprio(1);
#pragma unroll
            for (int mi = 0; mi < M_REP; mi++)
#pragma unroll
                for (int ni = 0; ni < 4; ni++)
                    acc[mi][ni] = __builtin_amdgcn_mfma_f32_16x16x32_bf16(af[mi], bf[ni], acc[mi][ni], 0, 0, 0);
            __builtin_amdgcn_s_setprio(0);
        }
        block_barrier();                       // all waves done reading buf[t&1]
        if (t + 2 < NT) stage(t + 2);          // refill the buffer just freed
    }

    const int crow = (lane >> 4) * 4;
    const int ccol = lane & 15;
#pragma unroll
    for (int mi = 0; mi < M_REP; mi++) {
#pragma unroll
        for (int j = 0; j < 4; j++) {
            long r = m0 + wm * (BM / 2) + mi * 16 + crow + j;
            float rowf = 0.0f;
            if (EPI == 1) rowf = scale * aux[(long)blockIdx.z * sAux + r];  // scale*keep
            if (EPI == 2) rowf = aux[(long)blockIdx.z * sAux + r];          // invsum
#pragma unroll
            for (int ni = 0; ni < 4; ni++) {
                long c = n0 + wn * 64 + ni * 16 + ccol;
                float v = acc[mi][ni][j];
                if (EPI == 0) {
                    ((unsigned short*)Cv)[(long)blockIdx.z * sC + r * ldc + c] = f2bf(v);
                } else if (EPI == 1) {
                    ((unsigned short*)Cv)[(long)blockIdx.z * sC + r * ldc + c] = f2bf(__expf(v * rowf));
                } else {
                    ((float*)Cv)[(long)blockIdx.z * sC + r * ldc + c] = v * rowf;
                }
            }
        }
    }
}

__global__ __launch_bounds__(512, 2) void gemm8_qkv(const unsigned short* __restrict__ A,
                                                    const unsigned short* __restrict__ B,
                                                    void* __restrict__ Cv,
                                                    int K, int lda, int ldb, int ldc,
                                                    long sA, long sB, long sC) {
    gemm8_body<0, 256>(A, B, Cv, nullptr, K, lda, ldb, ldc, sA, sB, sC, 0L, 1.0f);
}

__global__ __launch_bounds__(512, 2) void gemm8_scores(const unsigned short* __restrict__ A,
                                                       const unsigned short* __restrict__ B,
                                                       void* __restrict__ Cv,
                                                       const float* __restrict__ keep,
                                                       int K, int lda, int ldb, int ldc,
                                                       long sA, long sB, long sC, long sAux,
                                                       float scale) {
    gemm8_body<1, 256>(A, B, Cv, keep, K, lda, ldb, ldc, sA, sB, sC, sAux, scale);
}

__global__ __launch_bounds__(512, 2) void gemm8_pv(const unsigned short* __restrict__ A,
                                                   const unsigned short* __restrict__ B,
                                                   void* __restrict__ Cv,
                                                   const float* __restrict__ invsum,
                                                   int K, int lda, int ldb, int ldc,
                                                   long sA, long sB, long sC, long sAux) {
    gemm8_body<2, 128>(A, B, Cv, invsum, K, lda, ldb, ldc, sA, sB, sC, sAux, 1.0f);
}

// ---------------------------------------------------------------------------
// row sum of unnormalized bf16 P -> inverse sum (fp32), one block per row.
// ---------------------------------------------------------------------------
__global__ __launch_bounds__(256) void rowsum_inv(const unsigned short* __restrict__ P,
                                                  float* __restrict__ inv, long strideP) {
    const int tid = threadIdx.x;
    const long row = blockIdx.x;
    short8 v = ((const short8*)(P + row * strideP))[tid];
    float s = 0.0f;
#pragma unroll
    for (int i = 0; i < 8; i++) s += bf2f((unsigned short)v[i]);
#pragma unroll
    for (int i = 1; i < 64; i <<= 1) s += __shfl_xor(s, i);
    __shared__ float ss[4];
    if ((tid & 63) == 0) ss[tid >> 6] = s;
    __syncthreads();
    if (tid == 0) {
        float t = (ss[0] + ss[1]) + (ss[2] + ss[3]);
        inv[row] = 1.0f / t;
    }
}

// ---------------------------------------------------------------------------
extern "C" void kernel_launch(void* const* d_in, const int* in_sizes, int n_in,
                              void* d_out, int out_size, void* d_ws, size_t ws_size,
                              hipStream_t stream) {
    const float* x  = (const float*)d_in[0];
    const void*  mask = d_in[1];
    const float* qw = (const float*)d_in[2];
    const float* kw = (const float*)d_in[3];
    const float* vw = (const float*)d_in[4];
    float* out = (float*)d_out;

    constexpr int B = 4, S = 2048, D = 1024;
    constexpr long BS  = (long)B * S;      // 8192
    constexpr long BSD = BS * D;           // 8388608

    char* w = (char*)d_ws;
    auto alloc = [&](size_t bytes) {
        char* p = w;
        w += (bytes + 255) & ~(size_t)255;
        return p;
    };
    int*            flag    = (int*)alloc(256);
    float*          keep    = (float*)alloc(BS * 4);
    float*          invsum  = (float*)alloc(BS * 4);
    unsigned short* xb      = (unsigned short*)alloc((size_t)BSD * 2);
    unsigned short* wT      = (unsigned short*)alloc((size_t)3 * D * D * 2);
    unsigned short* qkv     = (unsigned short*)alloc((size_t)3 * BSD * 2);
    unsigned short* Qb = qkv;
    unsigned short* Kb = qkv + BSD;
    unsigned short* Vb = qkv + 2 * BSD;
    unsigned short* Vt      = (unsigned short*)alloc((size_t)BSD * 2);

    size_t base_used = (size_t)(w - (char*)d_ws);
    size_t pB = (size_t)B * S * S * 2;  // 32 MiB unnormalized P (bf16)
    bool batched = ws_size >= base_used + pB + 1024;

    unsigned short* P;
    if (batched) {
        P = (unsigned short*)alloc(pB);
    } else {
        P = (unsigned short*)alloc((size_t)S * S * 2);
    }

    const float scale = 0.03125f;  // 1/sqrt(1024), exact

    mask_detect<<<1, 256, 0, stream>>>((const unsigned char*)mask, flag);
    mask_expand<<<(int)(BS / 256), 256, 0, stream>>>(mask, flag, keep, (int)BS);
    convert_f32_bf16<<<(int)(BSD / 1024), 256, 0, stream>>>(x, xb, BSD / 4);
    transpose_w_kernel<<<dim3(32, 32, 3), dim3(32, 8), 0, stream>>>(qw, kw, vw, wT);

    // Q,K,V projections: M=8192, N=1024, K=1024; grid.z selects weight/output
    gemm8_qkv<<<dim3(32, 4, 3), 512, 0, stream>>>(xb, wT, qkv,
                                                  1024, 1024, 1024, 1024,
                                                  0L, (long)D * D, BSD);

    // V transpose: Vt[b][d][s]
    transpose_bf16<<<dim3(D / 32, S / 32, B), dim3(32, 8), 0, stream>>>(Vb, Vt, S, D,
                                                                        (long)S * D, (long)S * D);

    if (batched) {
        // P = exp(QK^T * scale * keep) unnormalized, bf16   (grid = 256 blocks)
        gemm8_scores<<<dim3(8, 8, B), 512, 0, stream>>>(Qb, Kb, P, keep,
                                                        1024, 1024, 1024, 2048,
                                                        (long)S * D, (long)S * D, (long)S * S, (long)S, scale);
        rowsum_inv<<<(int)BS, 256, 0, stream>>>(P, invsum, 2048);
        // out = (P * invsum[row]) . V   (BM=128 -> grid = 256 blocks)
        gemm8_pv<<<dim3(16, 4, B), 512, 0, stream>>>(P, Vt, out, invsum,
                                                     2048, 2048, 2048, 1024,
                                                     (long)S * S, (long)D * S, (long)S * D, (long)S);
    } else {
        for (int b = 0; b < B; b++) {
            gemm8_scores<<<dim3(8, 8, 1), 512, 0, stream>>>(Qb + (long)b * S * D, Kb + (long)b * S * D,
                                                            P, keep + (long)b * S,
                                                            1024, 1024, 1024, 2048,
                                                            0L, 0L, 0L, 0L, scale);
            rowsum_inv<<<S, 256, 0, stream>>>(P, invsum + (long)b * S, 2048);
            gemm8_pv<<<dim3(16, 4, 1), 512, 0, stream>>>(P, Vt + (long)b * D * S, out + (long)b * S * D,
                                                         invsum + (long)b * S,
                                                         2048, 2048, 2048, 1024,
                                                         0L, 0L, 0L, 0L);
        }
    }
}

// Round 5
// 187.727 us; speedup vs baseline: 1.2032x; 1.0566x over previous
//
#include <hip/hip_runtime.h>
#include <hip/hip_bf16.h>

typedef __attribute__((ext_vector_type(8))) short short8;
typedef __attribute__((ext_vector_type(4))) float floatx4;

struct ushort4v { unsigned short x, y, z, w; };

static __device__ __forceinline__ unsigned short f2bf(float f) {
    __hip_bfloat16 h = __float2bfloat16(f);
    return *reinterpret_cast<unsigned short*>(&h);
}

static __device__ __forceinline__ float bf2f(unsigned short u) {
    unsigned int v = ((unsigned int)u) << 16;
    return *reinterpret_cast<float*>(&v);
}

#define ASYNC_COPY16(gsrc, ldst)                                                            \
    __builtin_amdgcn_global_load_lds((const __attribute__((address_space(1))) void*)(gsrc), \
                                     (__attribute__((address_space(3))) void*)(ldst), 16, 0, 0)

static __device__ __forceinline__ void block_barrier() {
    asm volatile("" ::: "memory");
    __builtin_amdgcn_s_barrier();
    asm volatile("" ::: "memory");
}

// ---------------------------------------------------------------------------
__global__ void mask_detect(const unsigned char* __restrict__ m, int* __restrict__ flag) {
    __shared__ int s_or;
    if (threadIdx.x == 0) s_or = 0;
    __syncthreads();
    int acc = 0;
    for (int i = threadIdx.x; i < 8192; i += 256)
        if (i & 3) acc |= m[i];
    atomicOr(&s_or, acc);
    __syncthreads();
    if (threadIdx.x == 0) *flag = (s_or != 0) ? 1 : 0;  // 1 => u8 encoding
}

// keep[i] = 1.0f if attended, 0.0f if masked query row. exp(score*0)=1 for the
// whole row -> exactly-uniform softmax, identical to the reference where
// score*(1/32) + (-1e9) rounds to exactly -1e9 in fp32.
__global__ void mask_expand(const void* __restrict__ m, const int* __restrict__ flag,
                            float* __restrict__ keep, int n) {
    int i = blockIdx.x * 256 + threadIdx.x;
    if (i >= n) return;
    bool on;
    if (*flag)
        on = ((const unsigned char*)m)[i] != 0;
    else
        on = ((const int*)m)[i] != 0;
    keep[i] = on ? 1.0f : 0.0f;
}

// ---------------------------------------------------------------------------
__global__ __launch_bounds__(256) void convert_f32_bf16(const float* __restrict__ in,
                                                        unsigned short* __restrict__ out, long n4) {
    long i = (long)blockIdx.x * 256 + threadIdx.x;
    if (i >= n4) return;
    float4 v = ((const float4*)in)[i];
    ushort4v o;
    o.x = f2bf(v.x); o.y = f2bf(v.y); o.z = f2bf(v.z); o.w = f2bf(v.w);
    ((ushort4v*)out)[i] = o;
}

// ---------------------------------------------------------------------------
__global__ void transpose_w_kernel(const float* __restrict__ w0, const float* __restrict__ w1,
                                   const float* __restrict__ w2, unsigned short* __restrict__ out) {
    __shared__ float t[32][33];
    const float* w = blockIdx.z == 0 ? w0 : (blockIdx.z == 1 ? w1 : w2);
    unsigned short* o = out + (long)blockIdx.z * 1024 * 1024;
    int c0 = blockIdx.x * 32, r0 = blockIdx.y * 32;
    for (int i = threadIdx.y; i < 32; i += 8)
        t[i][threadIdx.x] = w[(long)(r0 + i) * 1024 + c0 + threadIdx.x];
    __syncthreads();
    for (int i = threadIdx.y; i < 32; i += 8)
        o[(long)(c0 + i) * 1024 + r0 + threadIdx.x] = f2bf(t[threadIdx.x][i]);
}

// ---------------------------------------------------------------------------
__global__ void transpose_bf16(const unsigned short* __restrict__ in, unsigned short* __restrict__ out,
                               int rows, int cols, long sIn, long sOut) {
    __shared__ unsigned short t[32][34];
    const unsigned short* ib = in + (long)blockIdx.z * sIn;
    unsigned short* ob = out + (long)blockIdx.z * sOut;
    int c0 = blockIdx.x * 32, r0 = blockIdx.y * 32;
    for (int i = threadIdx.y; i < 32; i += 8)
        t[i][threadIdx.x] = ib[(long)(r0 + i) * cols + c0 + threadIdx.x];
    __syncthreads();
    for (int i = threadIdx.y; i < 32; i += 8)
        ob[(long)(c0 + i) * rows + r0 + threadIdx.x] = t[threadIdx.x][i];
}

// ---------------------------------------------------------------------------
// Deep-pipelined GEMM: C[M,N] = A[M,K] * BT[N,K]^T  (bf16 in, fp32 accum)
// BM x 256 tile, BK=64, 8 waves (2M x 4N), per-wave (BM/2) x 64 output.
// Depth-2 double-buffer with counted vmcnt (never 0 in steady state).
// LDS swizzle (Guideline 4): byte ^= ((row&7)<<4) — involution applied to
// BOTH the pre-swizzled global source (global_load_lds writes linearly) and
// the ds_read address. 16 consecutive fragment rows -> 8 distinct 16B slots
// = 2-way bank aliasing (free, m136), vs 16-way in linear layout.
// EPI 0: bf16 C; EPI 1: bf16 exp(acc*scale*keep[row]); EPI 2: fp32 acc*inv[row].
// ---------------------------------------------------------------------------
template <int EPI, int BM>
static __device__ __forceinline__ void gemm8_body(const unsigned short* __restrict__ A,
                                                  const unsigned short* __restrict__ B,
                                                  void* __restrict__ Cv,
                                                  const float* __restrict__ aux,
                                                  int K, int lda, int ldb, int ldc,
                                                  long sA, long sB, long sC, long sAux,
                                                  float scale) {
    constexpr int M_REP = BM / 32;          // 8 (BM=256) or 4 (BM=128)
    constexpr int LA    = BM * 128 / 8192;  // A-tile loads per thread
    constexpr int LB    = 4;                // B-tile loads per thread
    constexpr int TILE  = (BM + 256) * 128; // bytes per K-tile buffer (A+B)
    __shared__ char sm[2 * TILE];

    const int tid = threadIdx.x;
    const int wid = tid >> 6, lane = tid & 63;
    const int wm  = wid >> 2, wn = wid & 3;       // 2 x 4 wave grid
    const int fr  = lane & 15, fk = lane >> 4;    // fragment row / 16B col unit
    const long m0 = (long)blockIdx.x * BM;
    const long n0 = (long)blockIdx.y * 256;
    const unsigned short* Ab = A + (long)blockIdx.z * sA + m0 * lda;
    const unsigned short* Bb = B + (long)blockIdx.z * sB + n0 * ldb;
    const int NT = K >> 6;

    floatx4 acc[M_REP][4] = {};

    auto stage = [&](int kt) {
        char* dA = sm + (kt & 1) * TILE;
        char* dB = dA + BM * 128;
        const int kb = kt << 6;
#pragma unroll
        for (int i = 0; i < LA; i++) {
            int lam = i * 8192 + tid * 16;                  // linear LDS byte (16-aligned)
            int lg  = lam ^ (((lam >> 7) & 7) << 4);        // logical byte (involution)
            ASYNC_COPY16(Ab + (long)(lg >> 7) * lda + kb + ((lg & 127) >> 1), dA + lam);
        }
#pragma unroll
        for (int i = 0; i < LB; i++) {
            int lam = i * 8192 + tid * 16;
            int lg  = lam ^ (((lam >> 7) & 7) << 4);
            ASYNC_COPY16(Bb + (long)(lg >> 7) * ldb + kb + ((lg & 127) >> 1), dB + lam);
        }
    };

    stage(0);
    stage(1);

    for (int t = 0; t < NT; t++) {
        // wait for tile t's loads (LA+LB per tile; up to 2 tiles in flight)
        if (t + 1 < NT) {
            if constexpr (BM == 256) asm volatile("s_waitcnt vmcnt(8)" ::: "memory");
            else                     asm volatile("s_waitcnt vmcnt(6)" ::: "memory");
        } else {
            asm volatile("s_waitcnt vmcnt(0)" ::: "memory");
        }
        block_barrier();                       // all waves' tile-t data resident

        const char* bA = sm + (t & 1) * TILE;
        const char* bB = bA + BM * 128;
#pragma unroll
        for (int ks = 0; ks < 2; ks++) {
            short8 af[M_REP], bf[4];
#pragma unroll
            for (int mi = 0; mi < M_REP; mi++) {
                int row = wm * (BM / 2) + mi * 16 + fr;
                int c   = (ks * 64 + fk * 16) ^ ((row & 7) << 4);
                af[mi] = *(const short8*)(bA + row * 128 + c);
            }
#pragma unroll
            for (int ni = 0; ni < 4; ni++) {
                int row = wn * 64 + ni * 16 + fr;
                int c   = (ks * 64 + fk * 16) ^ ((row & 7) << 4);
                bf[ni] = *(const short8*)(bB + row * 128 + c);
            }
            __builtin_amdgcn_s_setprio(1);
#pragma unroll
            for (int mi = 0; mi < M_REP; mi++)
#pragma unroll
                for (int ni = 0; ni < 4; ni++)
                    acc[mi][ni] = __builtin_amdgcn_mfma_f32_16x16x32_bf16(af[mi], bf[ni], acc[mi][ni], 0, 0, 0);
            __builtin_amdgcn_s_setprio(0);
        }
        block_barrier();                       // all waves done reading buf[t&1]
        if (t + 2 < NT) stage(t + 2);          // refill the buffer just freed
    }

    const int crow = (lane >> 4) * 4;
    const int ccol = lane & 15;
#pragma unroll
    for (int mi = 0; mi < M_REP; mi++) {
#pragma unroll
        for (int j = 0; j < 4; j++) {
            long r = m0 + wm * (BM / 2) + mi * 16 + crow + j;
            float rowf = 0.0f;
            if (EPI == 1) rowf = scale * aux[(long)blockIdx.z * sAux + r];  // scale*keep
            if (EPI == 2) rowf = aux[(long)blockIdx.z * sAux + r];          // invsum
#pragma unroll
            for (int ni = 0; ni < 4; ni++) {
                long c = n0 + wn * 64 + ni * 16 + ccol;
                float v = acc[mi][ni][j];
                if (EPI == 0) {
                    ((unsigned short*)Cv)[(long)blockIdx.z * sC + r * ldc + c] = f2bf(v);
                } else if (EPI == 1) {
                    ((unsigned short*)Cv)[(long)blockIdx.z * sC + r * ldc + c] = f2bf(__expf(v * rowf));
                } else {
                    ((float*)Cv)[(long)blockIdx.z * sC + r * ldc + c] = v * rowf;
                }
            }
        }
    }
}

__global__ __launch_bounds__(512, 2) void gemm8_qkv(const unsigned short* __restrict__ A,
                                                    const unsigned short* __restrict__ B,
                                                    void* __restrict__ Cv,
                                                    int K, int lda, int ldb, int ldc,
                                                    long sA, long sB, long sC) {
    gemm8_body<0, 128>(A, B, Cv, nullptr, K, lda, ldb, ldc, sA, sB, sC, 0L, 1.0f);
}

__global__ __launch_bounds__(512, 2) void gemm8_scores(const unsigned short* __restrict__ A,
                                                       const unsigned short* __restrict__ B,
                                                       void* __restrict__ Cv,
                                                       const float* __restrict__ keep,
                                                       int K, int lda, int ldb, int ldc,
                                                       long sA, long sB, long sC, long sAux,
                                                       float scale) {
    gemm8_body<1, 256>(A, B, Cv, keep, K, lda, ldb, ldc, sA, sB, sC, sAux, scale);
}

__global__ __launch_bounds__(512, 2) void gemm8_pv(const unsigned short* __restrict__ A,
                                                   const unsigned short* __restrict__ B,
                                                   void* __restrict__ Cv,
                                                   const float* __restrict__ invsum,
                                                   int K, int lda, int ldb, int ldc,
                                                   long sA, long sB, long sC, long sAux) {
    gemm8_body<2, 128>(A, B, Cv, invsum, K, lda, ldb, ldc, sA, sB, sC, sAux, 1.0f);
}

// ---------------------------------------------------------------------------
__global__ __launch_bounds__(256) void rowsum_inv(const unsigned short* __restrict__ P,
                                                  float* __restrict__ inv, long strideP) {
    const int tid = threadIdx.x;
    const long row = blockIdx.x;
    short8 v = ((const short8*)(P + row * strideP))[tid];
    float s = 0.0f;
#pragma unroll
    for (int i = 0; i < 8; i++) s += bf2f((unsigned short)v[i]);
#pragma unroll
    for (int i = 1; i < 64; i <<= 1) s += __shfl_xor(s, i);
    __shared__ float ss[4];
    if ((tid & 63) == 0) ss[tid >> 6] = s;
    __syncthreads();
    if (tid == 0) {
        float t = (ss[0] + ss[1]) + (ss[2] + ss[3]);
        inv[row] = 1.0f / t;
    }
}

// ---------------------------------------------------------------------------
extern "C" void kernel_launch(void* const* d_in, const int* in_sizes, int n_in,
                              void* d_out, int out_size, void* d_ws, size_t ws_size,
                              hipStream_t stream) {
    const float* x  = (const float*)d_in[0];
    const void*  mask = d_in[1];
    const float* qw = (const float*)d_in[2];
    const float* kw = (const float*)d_in[3];
    const float* vw = (const float*)d_in[4];
    float* out = (float*)d_out;

    constexpr int B = 4, S = 2048, D = 1024;
    constexpr long BS  = (long)B * S;      // 8192
    constexpr long BSD = BS * D;           // 8388608

    char* w = (char*)d_ws;
    auto alloc = [&](size_t bytes) {
        char* p = w;
        w += (bytes + 255) & ~(size_t)255;
        return p;
    };
    int*            flag    = (int*)alloc(256);
    float*          keep    = (float*)alloc(BS * 4);
    float*          invsum  = (float*)alloc(BS * 4);
    unsigned short* xb      = (unsigned short*)alloc((size_t)BSD * 2);
    unsigned short* wT      = (unsigned short*)alloc((size_t)3 * D * D * 2);
    unsigned short* qkv     = (unsigned short*)alloc((size_t)3 * BSD * 2);
    unsigned short* Qb = qkv;
    unsigned short* Kb = qkv + BSD;
    unsigned short* Vb = qkv + 2 * BSD;
    unsigned short* Vt      = (unsigned short*)alloc((size_t)BSD * 2);

    size_t base_used = (size_t)(w - (char*)d_ws);
    size_t pB = (size_t)B * S * S * 2;  // 32 MiB unnormalized P (bf16)
    bool batched = ws_size >= base_used + pB + 1024;

    unsigned short* P;
    if (batched) {
        P = (unsigned short*)alloc(pB);
    } else {
        P = (unsigned short*)alloc((size_t)S * S * 2);
    }

    const float scale = 0.03125f;  // 1/sqrt(1024), exact

    mask_detect<<<1, 256, 0, stream>>>((const unsigned char*)mask, flag);
    mask_expand<<<(int)(BS / 256), 256, 0, stream>>>(mask, flag, keep, (int)BS);
    convert_f32_bf16<<<(int)(BSD / 1024), 256, 0, stream>>>(x, xb, BSD / 4);
    transpose_w_kernel<<<dim3(32, 32, 3), dim3(32, 8), 0, stream>>>(qw, kw, vw, wT);

    // Q,K,V projections: BM=128 -> 64x4x3 = 768 blocks = exactly 3 full rounds
    gemm8_qkv<<<dim3(64, 4, 3), 512, 0, stream>>>(xb, wT, qkv,
                                                  1024, 1024, 1024, 1024,
                                                  0L, (long)D * D, BSD);

    // V transpose: Vt[b][d][s]
    transpose_bf16<<<dim3(D / 32, S / 32, B), dim3(32, 8), 0, stream>>>(Vb, Vt, S, D,
                                                                        (long)S * D, (long)S * D);

    if (batched) {
        // P = exp(QK^T * scale * keep) unnormalized, bf16   (grid = 256 blocks)
        gemm8_scores<<<dim3(8, 8, B), 512, 0, stream>>>(Qb, Kb, P, keep,
                                                        1024, 1024, 1024, 2048,
                                                        (long)S * D, (long)S * D, (long)S * S, (long)S, scale);
        rowsum_inv<<<(int)BS, 256, 0, stream>>>(P, invsum, 2048);
        // out = (P * invsum[row]) . V   (BM=128 -> grid = 256 blocks)
        gemm8_pv<<<dim3(16, 4, B), 512, 0, stream>>>(P, Vt, out, invsum,
                                                     2048, 2048, 2048, 1024,
                                                     (long)S * S, (long)D * S, (long)S * D, (long)S);
    } else {
        for (int b = 0; b < B; b++) {
            gemm8_scores<<<dim3(8, 8, 1), 512, 0, stream>>>(Qb + (long)b * S * D, Kb + (long)b * S * D,
                                                            P, keep + (long)b * S,
                                                            1024, 1024, 1024, 2048,
                                                            0L, 0L, 0L, 0L, scale);
            rowsum_inv<<<S, 256, 0, stream>>>(P, invsum + (long)b * S, 2048);
            gemm8_pv<<<dim3(16, 4, 1), 512, 0, stream>>>(P, Vt + (long)b * D * S, out + (long)b * S * D,
                                                         invsum + (long)b * S,
                                                         2048, 2048, 2048, 1024,
                                                         0L, 0L, 0L, 0L);
        }
    }
}

// Round 7
// 186.309 us; speedup vs baseline: 1.2124x; 1.0076x over previous
//
#include <hip/hip_runtime.h>
#include <hip/hip_bf16.h>

typedef __attribute__((ext_vector_type(8))) short short8;
typedef __attribute__((ext_vector_type(4))) float floatx4;

struct ushort4v { unsigned short x, y, z, w; };

static __device__ __forceinline__ unsigned short f2bf(float f) {
    __hip_bfloat16 h = __float2bfloat16(f);
    return *reinterpret_cast<unsigned short*>(&h);
}

static __device__ __forceinline__ float bf2f(unsigned short u) {
    unsigned int v = ((unsigned int)u) << 16;
    return *reinterpret_cast<float*>(&v);
}

#define ASYNC_COPY16(gsrc, ldst)                                                            \
    __builtin_amdgcn_global_load_lds((const __attribute__((address_space(1))) void*)(gsrc), \
                                     (__attribute__((address_space(3))) void*)(ldst), 16, 0, 0)

static __device__ __forceinline__ void block_barrier() {
    asm volatile("" ::: "memory");
    __builtin_amdgcn_s_barrier();
    asm volatile("" ::: "memory");
}

// ---------------------------------------------------------------------------
__global__ void mask_detect(const unsigned char* __restrict__ m, int* __restrict__ flag) {
    __shared__ int s_or;
    if (threadIdx.x == 0) s_or = 0;
    __syncthreads();
    int acc = 0;
    for (int i = threadIdx.x; i < 8192; i += 256)
        if (i & 3) acc |= m[i];
    atomicOr(&s_or, acc);
    __syncthreads();
    if (threadIdx.x == 0) *flag = (s_or != 0) ? 1 : 0;  // 1 => u8 encoding
}

// keep[i] = 1.0f if attended, 0.0f if masked query row. exp(score*0)=1 for the
// whole row -> exactly-uniform softmax, identical to the reference where
// score*(1/32) + (-1e9) rounds to exactly -1e9 in fp32.
__global__ void mask_expand(const void* __restrict__ m, const int* __restrict__ flag,
                            float* __restrict__ keep, int n) {
    int i = blockIdx.x * 256 + threadIdx.x;
    if (i >= n) return;
    bool on;
    if (*flag)
        on = ((const unsigned char*)m)[i] != 0;
    else
        on = ((const int*)m)[i] != 0;
    keep[i] = on ? 1.0f : 0.0f;
}

// ---------------------------------------------------------------------------
__global__ __launch_bounds__(256) void convert_f32_bf16(const float* __restrict__ in,
                                                        unsigned short* __restrict__ out, long n4) {
    long i = (long)blockIdx.x * 256 + threadIdx.x;
    if (i >= n4) return;
    float4 v = ((const float4*)in)[i];
    ushort4v o;
    o.x = f2bf(v.x); o.y = f2bf(v.y); o.z = f2bf(v.z); o.w = f2bf(v.w);
    ((ushort4v*)out)[i] = o;
}

// ---------------------------------------------------------------------------
__global__ void transpose_w_kernel(const float* __restrict__ w0, const float* __restrict__ w1,
                                   const float* __restrict__ w2, unsigned short* __restrict__ out) {
    __shared__ float t[32][33];
    const float* w = blockIdx.z == 0 ? w0 : (blockIdx.z == 1 ? w1 : w2);
    unsigned short* o = out + (long)blockIdx.z * 1024 * 1024;
    int c0 = blockIdx.x * 32, r0 = blockIdx.y * 32;
    for (int i = threadIdx.y; i < 32; i += 8)
        t[i][threadIdx.x] = w[(long)(r0 + i) * 1024 + c0 + threadIdx.x];
    __syncthreads();
    for (int i = threadIdx.y; i < 32; i += 8)
        o[(long)(c0 + i) * 1024 + r0 + threadIdx.x] = f2bf(t[threadIdx.x][i]);
}

// ---------------------------------------------------------------------------
__global__ void transpose_bf16(const unsigned short* __restrict__ in, unsigned short* __restrict__ out,
                               int rows, int cols, long sIn, long sOut) {
    __shared__ unsigned short t[32][34];
    const unsigned short* ib = in + (long)blockIdx.z * sIn;
    unsigned short* ob = out + (long)blockIdx.z * sOut;
    int c0 = blockIdx.x * 32, r0 = blockIdx.y * 32;
    for (int i = threadIdx.y; i < 32; i += 8)
        t[i][threadIdx.x] = ib[(long)(r0 + i) * cols + c0 + threadIdx.x];
    __syncthreads();
    for (int i = threadIdx.y; i < 32; i += 8)
        ob[(long)(c0 + i) * rows + r0 + threadIdx.x] = t[threadIdx.x][i];
}

// ---------------------------------------------------------------------------
// Deep-pipelined GEMM: C[M,N] = A[M,K] * BT[N,K]^T  (bf16 in, fp32 accum)
// 128x256 tile, BK=32, 8 waves (2M x 4N), per-wave 64x64 output.
// Depth-3 LDS ring (3 x 24KB = 72KB -> 2 blocks/CU = 16 waves/CU) with
// counted vmcnt (steady vmcnt(6); tail 3/0 per remaining-tiles accounting).
// LDS rows are 64B (BK=32): swizzle c ^= ((row>>1)&3)<<4 — slot bits from
// row bits 1..2 so bank = 16*(r&1) + 4*slot covers all 32 banks over 16
// consecutive fragment rows (2-way = free). Involution applied to BOTH the
// pre-swizzled global source (global_load_lds writes linearly) and ds_read.
// EPI 0: bf16 C; EPI 1: bf16 exp(acc*scale*keep[row]); EPI 2: fp32 acc*inv[row].
// ---------------------------------------------------------------------------
template <int EPI>
static __device__ __forceinline__ void gemm8_body(const unsigned short* __restrict__ A,
                                                  const unsigned short* __restrict__ B,
                                                  void* __restrict__ Cv,
                                                  const float* __restrict__ aux,
                                                  int K, int lda, int ldb, int ldc,
                                                  long sA, long sB, long sC, long sAux,
                                                  float scale) {
    constexpr int TILE = (128 + 256) * 32 * 2;  // 24576 B per K-tile (A+B)
    __shared__ char sm[3 * TILE];

    const int tid = threadIdx.x;
    const int wid = tid >> 6, lane = tid & 63;
    const int wm  = wid >> 2, wn = wid & 3;       // 2 x 4 wave grid
    const int fr  = lane & 15, fk = lane >> 4;    // fragment row / 16B col unit
    const long m0 = (long)blockIdx.x * 128;
    const long n0 = (long)blockIdx.y * 256;
    const unsigned short* Ab = A + (long)blockIdx.z * sA + m0 * lda;
    const unsigned short* Bb = B + (long)blockIdx.z * sB + n0 * ldb;
    const int NT = K >> 5;

    floatx4 acc[4][4] = {};

    auto stage = [&](int kt, int buf) {
        char* dA = sm + buf * TILE;
        char* dB = dA + 128 * 64;                 // A part = 8192 B
        const int kb = kt << 5;
        {
            int lam = tid * 16;                                // linear LDS byte
            int lg  = lam ^ (((lam >> 7) & 3) << 4);           // logical (involution)
            ASYNC_COPY16(Ab + (long)(lg >> 6) * lda + kb + ((lg & 63) >> 1), dA + lam);
        }
#pragma unroll
        for (int i = 0; i < 2; i++) {
            int lam = i * 8192 + tid * 16;
            int lg  = lam ^ (((lam >> 7) & 3) << 4);
            ASYNC_COPY16(Bb + (long)(lg >> 6) * ldb + kb + ((lg & 63) >> 1), dB + lam);
        }
    };

    stage(0, 0);
    stage(1, 1);
    stage(2, 2);

    int cur = 0;
    for (int t = 0; t < NT; t++) {
        // drain tile t's 3 loads; keep newer tiles' loads in flight
        const int nf = NT - 1 - t;  // newer tiles currently staged
        if (nf >= 2)      asm volatile("s_waitcnt vmcnt(6)" ::: "memory");
        else if (nf == 1) asm volatile("s_waitcnt vmcnt(3)" ::: "memory");
        else              asm volatile("s_waitcnt vmcnt(0)" ::: "memory");
        block_barrier();                       // all waves' tile-t data resident

        const char* bA = sm + cur * TILE;
        const char* bB = bA + 128 * 64;
        short8 af[4], bf[4];
#pragma unroll
        for (int mi = 0; mi < 4; mi++) {
            int row = wm * 64 + mi * 16 + fr;
            int c   = (fk * 16) ^ (((row >> 1) & 3) << 4);
            af[mi] = *(const short8*)(bA + row * 64 + c);
        }
#pragma unroll
        for (int ni = 0; ni < 4; ni++) {
            int row = wn * 64 + ni * 16 + fr;
            int c   = (fk * 16) ^ (((row >> 1) & 3) << 4);
            bf[ni] = *(const short8*)(bB + row * 64 + c);
        }
        __builtin_amdgcn_s_setprio(1);
#pragma unroll
        for (int mi = 0; mi < 4; mi++)
#pragma unroll
            for (int ni = 0; ni < 4; ni++)
                acc[mi][ni] = __builtin_amdgcn_mfma_f32_16x16x32_bf16(af[mi], bf[ni], acc[mi][ni], 0, 0, 0);
        __builtin_amdgcn_s_setprio(0);
        block_barrier();                       // all waves done reading buf[cur]
        if (t + 3 < NT) stage(t + 3, cur);     // refill the buffer just freed
        cur = (cur == 2) ? 0 : cur + 1;
    }

    const int crow = (lane >> 4) * 4;
    const int ccol = lane & 15;
#pragma unroll
    for (int mi = 0; mi < 4; mi++) {
#pragma unroll
        for (int j = 0; j < 4; j++) {
            long r = m0 + wm * 64 + mi * 16 + crow + j;
            float rowf = 0.0f;
            if (EPI == 1) rowf = scale * aux[(long)blockIdx.z * sAux + r];  // scale*keep
            if (EPI == 2) rowf = aux[(long)blockIdx.z * sAux + r];          // invsum
#pragma unroll
            for (int ni = 0; ni < 4; ni++) {
                long c = n0 + wn * 64 + ni * 16 + ccol;
                float v = acc[mi][ni][j];
                if (EPI == 0) {
                    ((unsigned short*)Cv)[(long)blockIdx.z * sC + r * ldc + c] = f2bf(v);
                } else if (EPI == 1) {
                    ((unsigned short*)Cv)[(long)blockIdx.z * sC + r * ldc + c] = f2bf(__expf(v * rowf));
                } else {
                    ((float*)Cv)[(long)blockIdx.z * sC + r * ldc + c] = v * rowf;
                }
            }
        }
    }
}

__global__ __launch_bounds__(512, 4) void gemm8_qkv(const unsigned short* __restrict__ A,
                                                    const unsigned short* __restrict__ B,
                                                    void* __restrict__ Cv,
                                                    int K, int lda, int ldb, int ldc,
                                                    long sA, long sB, long sC) {
    gemm8_body<0>(A, B, Cv, nullptr, K, lda, ldb, ldc, sA, sB, sC, 0L, 1.0f);
}

__global__ __launch_bounds__(512, 4) void gemm8_scores(const unsigned short* __restrict__ A,
                                                       const unsigned short* __restrict__ B,
                                                       void* __restrict__ Cv,
                                                       const float* __restrict__ keep,
                                                       int K, int lda, int ldb, int ldc,
                                                       long sA, long sB, long sC, long sAux,
                                                       float scale) {
    gemm8_body<1>(A, B, Cv, keep, K, lda, ldb, ldc, sA, sB, sC, sAux, scale);
}

__global__ __launch_bounds__(512, 4) void gemm8_pv(const unsigned short* __restrict__ A,
                                                   const unsigned short* __restrict__ B,
                                                   void* __restrict__ Cv,
                                                   const float* __restrict__ invsum,
                                                   int K, int lda, int ldb, int ldc,
                                                   long sA, long sB, long sC, long sAux) {
    gemm8_body<2>(A, B, Cv, invsum, K, lda, ldb, ldc, sA, sB, sC, sAux, 1.0f);
}

// ---------------------------------------------------------------------------
__global__ __launch_bounds__(256) void rowsum_inv(const unsigned short* __restrict__ P,
                                                  float* __restrict__ inv, long strideP) {
    const int tid = threadIdx.x;
    const long row = blockIdx.x;
    short8 v = ((const short8*)(P + row * strideP))[tid];
    float s = 0.0f;
#pragma unroll
    for (int i = 0; i < 8; i++) s += bf2f((unsigned short)v[i]);
#pragma unroll
    for (int i = 1; i < 64; i <<= 1) s += __shfl_xor(s, i);
    __shared__ float ss[4];
    if ((tid & 63) == 0) ss[tid >> 6] = s;
    __syncthreads();
    if (tid == 0) {
        float t = (ss[0] + ss[1]) + (ss[2] + ss[3]);
        inv[row] = 1.0f / t;
    }
}

// ---------------------------------------------------------------------------
extern "C" void kernel_launch(void* const* d_in, const int* in_sizes, int n_in,
                              void* d_out, int out_size, void* d_ws, size_t ws_size,
                              hipStream_t stream) {
    const float* x  = (const float*)d_in[0];
    const void*  mask = d_in[1];
    const float* qw = (const float*)d_in[2];
    const float* kw = (const float*)d_in[3];
    const float* vw = (const float*)d_in[4];
    float* out = (float*)d_out;

    constexpr int B = 4, S = 2048, D = 1024;
    constexpr long BS  = (long)B * S;      // 8192
    constexpr long BSD = BS * D;           // 8388608

    char* w = (char*)d_ws;
    auto alloc = [&](size_t bytes) {
        char* p = w;
        w += (bytes + 255) & ~(size_t)255;
        return p;
    };
    int*            flag    = (int*)alloc(256);
    float*          keep    = (float*)alloc(BS * 4);
    float*          invsum  = (float*)alloc(BS * 4);
    unsigned short* xb      = (unsigned short*)alloc((size_t)BSD * 2);
    unsigned short* wT      = (unsigned short*)alloc((size_t)3 * D * D * 2);
    unsigned short* qkv     = (unsigned short*)alloc((size_t)3 * BSD * 2);
    unsigned short* Qb = qkv;
    unsigned short* Kb = qkv + BSD;
    unsigned short* Vb = qkv + 2 * BSD;
    unsigned short* Vt      = (unsigned short*)alloc((size_t)BSD * 2);

    size_t base_used = (size_t)(w - (char*)d_ws);
    size_t pB = (size_t)B * S * S * 2;  // 32 MiB unnormalized P (bf16)
    bool batched = ws_size >= base_used + pB + 1024;

    unsigned short* P;
    if (batched) {
        P = (unsigned short*)alloc(pB);
    } else {
        P = (unsigned short*)alloc((size_t)S * S * 2);
    }

    const float scale = 0.03125f;  // 1/sqrt(1024), exact

    mask_detect<<<1, 256, 0, stream>>>((const unsigned char*)mask, flag);
    mask_expand<<<(int)(BS / 256), 256, 0, stream>>>(mask, flag, keep, (int)BS);
    convert_f32_bf16<<<(int)(BSD / 1024), 256, 0, stream>>>(x, xb, BSD / 4);
    transpose_w_kernel<<<dim3(32, 32, 3), dim3(32, 8), 0, stream>>>(qw, kw, vw, wT);

    // Q,K,V projections: 64x4x3 = 768 blocks, 2 blocks/CU -> balanced 3/CU
    gemm8_qkv<<<dim3(64, 4, 3), 512, 0, stream>>>(xb, wT, qkv,
                                                  1024, 1024, 1024, 1024,
                                                  0L, (long)D * D, BSD);

    // V transpose: Vt[b][d][s]
    transpose_bf16<<<dim3(D / 32, S / 32, B), dim3(32, 8), 0, stream>>>(Vb, Vt, S, D,
                                                                        (long)S * D, (long)S * D);

    if (batched) {
        // P = exp(QK^T * scale * keep) unnormalized, bf16  (512 blocks = one 2/CU round)
        gemm8_scores<<<dim3(16, 8, B), 512, 0, stream>>>(Qb, Kb, P, keep,
                                                         1024, 1024, 1024, 2048,
                                                         (long)S * D, (long)S * D, (long)S * S, (long)S, scale);
        rowsum_inv<<<(int)BS, 256, 0, stream>>>(P, invsum, 2048);
        // out = (P * invsum[row]) . V   (256 blocks -> full CU coverage)
        gemm8_pv<<<dim3(16, 4, B), 512, 0, stream>>>(P, Vt, out, invsum,
                                                     2048, 2048, 2048, 1024,
                                                     (long)S * S, (long)D * S, (long)S * D, (long)S);
    } else {
        for (int b = 0; b < B; b++) {
            gemm8_scores<<<dim3(16, 8, 1), 512, 0, stream>>>(Qb + (long)b * S * D, Kb + (long)b * S * D,
                                                             P, keep + (long)b * S,
                                                             1024, 1024, 1024, 2048,
                                                             0L, 0L, 0L, 0L, scale);
            rowsum_inv<<<S, 256, 0, stream>>>(P, invsum + (long)b * S, 2048);
            gemm8_pv<<<dim3(16, 4, 1), 512, 0, stream>>>(P, Vt + (long)b * D * S, out + (long)b * S * D,
                                                         invsum + (long)b * S,
                                                         2048, 2048, 2048, 1024,
                                                         0L, 0L, 0L, 0L);
        }
    }
}

// Round 8
// 178.598 us; speedup vs baseline: 1.2647x; 1.0432x over previous
//
#include <hip/hip_runtime.h>
#include <hip/hip_bf16.h>

typedef __attribute__((ext_vector_type(8))) short short8;
typedef __attribute__((ext_vector_type(4))) float floatx4;

struct ushort4v { unsigned short x, y, z, w; };

static __device__ __forceinline__ unsigned short f2bf(float f) {
    __hip_bfloat16 h = __float2bfloat16(f);
    return *reinterpret_cast<unsigned short*>(&h);
}

static __device__ __forceinline__ float bf2f(unsigned short u) {
    unsigned int v = ((unsigned int)u) << 16;
    return *reinterpret_cast<float*>(&v);
}

#define ASYNC_COPY16(gsrc, ldst)                                                            \
    __builtin_amdgcn_global_load_lds((const __attribute__((address_space(1))) void*)(gsrc), \
                                     (__attribute__((address_space(3))) void*)(ldst), 16, 0, 0)

static __device__ __forceinline__ void block_barrier() {
    asm volatile("" ::: "memory");
    __builtin_amdgcn_s_barrier();
    asm volatile("" ::: "memory");
}

// ---------------------------------------------------------------------------
__global__ void mask_detect(const unsigned char* __restrict__ m, int* __restrict__ flag) {
    __shared__ int s_or;
    if (threadIdx.x == 0) s_or = 0;
    __syncthreads();
    int acc = 0;
    for (int i = threadIdx.x; i < 8192; i += 256)
        if (i & 3) acc |= m[i];
    atomicOr(&s_or, acc);
    __syncthreads();
    if (threadIdx.x == 0) *flag = (s_or != 0) ? 1 : 0;  // 1 => u8 encoding
}

// keep[i] = 1.0f if attended, 0.0f if masked query row. exp(score*0)=1 for the
// whole row -> exactly-uniform softmax, identical to the reference where
// score*(1/32) + (-1e9) rounds to exactly -1e9 in fp32.
__global__ void mask_expand(const void* __restrict__ m, const int* __restrict__ flag,
                            float* __restrict__ keep, int n) {
    int i = blockIdx.x * 256 + threadIdx.x;
    if (i >= n) return;
    bool on;
    if (*flag)
        on = ((const unsigned char*)m)[i] != 0;
    else
        on = ((const int*)m)[i] != 0;
    keep[i] = on ? 1.0f : 0.0f;
}

// ---------------------------------------------------------------------------
__global__ __launch_bounds__(256) void convert_f32_bf16(const float* __restrict__ in,
                                                        unsigned short* __restrict__ out, long n4) {
    long i = (long)blockIdx.x * 256 + threadIdx.x;
    if (i >= n4) return;
    float4 v = ((const float4*)in)[i];
    ushort4v o;
    o.x = f2bf(v.x); o.y = f2bf(v.y); o.z = f2bf(v.z); o.w = f2bf(v.w);
    ((ushort4v*)out)[i] = o;
}

// ---------------------------------------------------------------------------
__global__ void transpose_w_kernel(const float* __restrict__ w0, const float* __restrict__ w1,
                                   const float* __restrict__ w2, unsigned short* __restrict__ out) {
    __shared__ float t[32][33];
    const float* w = blockIdx.z == 0 ? w0 : (blockIdx.z == 1 ? w1 : w2);
    unsigned short* o = out + (long)blockIdx.z * 1024 * 1024;
    int c0 = blockIdx.x * 32, r0 = blockIdx.y * 32;
    for (int i = threadIdx.y; i < 32; i += 8)
        t[i][threadIdx.x] = w[(long)(r0 + i) * 1024 + c0 + threadIdx.x];
    __syncthreads();
    for (int i = threadIdx.y; i < 32; i += 8)
        o[(long)(c0 + i) * 1024 + r0 + threadIdx.x] = f2bf(t[threadIdx.x][i]);
}

// ---------------------------------------------------------------------------
__global__ void transpose_bf16(const unsigned short* __restrict__ in, unsigned short* __restrict__ out,
                               int rows, int cols, long sIn, long sOut) {
    __shared__ unsigned short t[32][34];
    const unsigned short* ib = in + (long)blockIdx.z * sIn;
    unsigned short* ob = out + (long)blockIdx.z * sOut;
    int c0 = blockIdx.x * 32, r0 = blockIdx.y * 32;
    for (int i = threadIdx.y; i < 32; i += 8)
        t[i][threadIdx.x] = ib[(long)(r0 + i) * cols + c0 + threadIdx.x];
    __syncthreads();
    for (int i = threadIdx.y; i < 32; i += 8)
        ob[(long)(c0 + i) * rows + r0 + threadIdx.x] = t[threadIdx.x][i];
}

// ---------------------------------------------------------------------------
// Deep-pipelined GEMM: C[M,N] = A[M,K] * BT[N,K]^T  (bf16 in, fp32 accum)
// 128x256 tile, BK=32, 8 waves (2M x 4N), per-wave 64x64 output.
// Depth-3 LDS ring (72KB -> 2 blocks/CU), ONE barrier per K-step:
//   {vmcnt(3|0), barrier, ds_read(t), stage(t+2 -> freed buf), MFMA(t)}
// Safety: a wave passes barrier(t) only after its iter-(t-1) MFMAs issued,
// which are lgkmcnt-gated on its iter-(t-1) ds_reads -> all reads of tile
// t-1 returned before any wave stages into buf[(t-1)%3] == buf[(t+2)%3].
// vmcnt ledger: steady outstanding = {t, t+1} = 6 loads; drain t -> vmcnt(3).
// LDS rows 64B: swizzle c ^= ((row>>1)&3)<<4 (involution, both sides).
// EPI 0: bf16 C; EPI 1: bf16 exp(acc*scale*keep[row]); EPI 2: fp32 acc*inv[row].
// ---------------------------------------------------------------------------
template <int EPI>
static __device__ __forceinline__ void gemm8_body(const unsigned short* __restrict__ A,
                                                  const unsigned short* __restrict__ B,
                                                  void* __restrict__ Cv,
                                                  const float* __restrict__ aux,
                                                  int K, int lda, int ldb, int ldc,
                                                  long sA, long sB, long sC, long sAux,
                                                  float scale) {
    constexpr int TILE = (128 + 256) * 32 * 2;  // 24576 B per K-tile (A+B)
    __shared__ char sm[3 * TILE];

    const int tid = threadIdx.x;
    const int wid = tid >> 6, lane = tid & 63;
    const int wm  = wid >> 2, wn = wid & 3;       // 2 x 4 wave grid
    const int fr  = lane & 15, fk = lane >> 4;    // fragment row / 16B col unit
    const long m0 = (long)blockIdx.x * 128;
    const long n0 = (long)blockIdx.y * 256;
    const unsigned short* Ab = A + (long)blockIdx.z * sA + m0 * lda;
    const unsigned short* Bb = B + (long)blockIdx.z * sB + n0 * ldb;
    const int NT = K >> 5;

    floatx4 acc[4][4] = {};

    auto stage = [&](int kt, int buf) {
        char* dA = sm + buf * TILE;
        char* dB = dA + 128 * 64;                 // A part = 8192 B
        const int kb = kt << 5;
        {
            int lam = tid * 16;                                // linear LDS byte
            int lg  = lam ^ (((lam >> 7) & 3) << 4);           // logical (involution)
            ASYNC_COPY16(Ab + (long)(lg >> 6) * lda + kb + ((lg & 63) >> 1), dA + lam);
        }
#pragma unroll
        for (int i = 0; i < 2; i++) {
            int lam = i * 8192 + tid * 16;
            int lg  = lam ^ (((lam >> 7) & 3) << 4);
            ASYNC_COPY16(Bb + (long)(lg >> 6) * ldb + kb + ((lg & 63) >> 1), dB + lam);
        }
    };

    stage(0, 0);
    stage(1, 1);

    int cur = 0;
    for (int t = 0; t < NT; t++) {
        // drain tile t's 3 loads; keep tile t+1's in flight
        if (t + 1 < NT) asm volatile("s_waitcnt vmcnt(3)" ::: "memory");
        else            asm volatile("s_waitcnt vmcnt(0)" ::: "memory");
        block_barrier();   // after this, every wave's reads of tile t-1 returned

        const char* bA = sm + cur * TILE;
        const char* bB = bA + 128 * 64;
        short8 af[4], bf[4];
#pragma unroll
        for (int mi = 0; mi < 4; mi++) {
            int row = wm * 64 + mi * 16 + fr;
            int c   = (fk * 16) ^ (((row >> 1) & 3) << 4);
            af[mi] = *(const short8*)(bA + row * 64 + c);
        }
#pragma unroll
        for (int ni = 0; ni < 4; ni++) {
            int row = wn * 64 + ni * 16 + fr;
            int c   = (fk * 16) ^ (((row >> 1) & 3) << 4);
            bf[ni] = *(const short8*)(bB + row * 64 + c);
        }
        if (t + 2 < NT) stage(t + 2, (cur + 2) % 3);   // refill buf freed at this barrier

        __builtin_amdgcn_s_setprio(1);
#pragma unroll
        for (int mi = 0; mi < 4; mi++)
#pragma unroll
            for (int ni = 0; ni < 4; ni++)
                acc[mi][ni] = __builtin_amdgcn_mfma_f32_16x16x32_bf16(af[mi], bf[ni], acc[mi][ni], 0, 0, 0);
        __builtin_amdgcn_s_setprio(0);
        cur = (cur == 2) ? 0 : cur + 1;
    }

    const int crow = (lane >> 4) * 4;
    const int ccol = lane & 15;
#pragma unroll
    for (int mi = 0; mi < 4; mi++) {
#pragma unroll
        for (int j = 0; j < 4; j++) {
            long r = m0 + wm * 64 + mi * 16 + crow + j;
            float rowf = 0.0f;
            if (EPI == 1) rowf = scale * aux[(long)blockIdx.z * sAux + r];  // scale*keep
            if (EPI == 2) rowf = aux[(long)blockIdx.z * sAux + r];          // invsum
#pragma unroll
            for (int ni = 0; ni < 4; ni++) {
                long c = n0 + wn * 64 + ni * 16 + ccol;
                float v = acc[mi][ni][j];
                if (EPI == 0) {
                    ((unsigned short*)Cv)[(long)blockIdx.z * sC + r * ldc + c] = f2bf(v);
                } else if (EPI == 1) {
                    ((unsigned short*)Cv)[(long)blockIdx.z * sC + r * ldc + c] = f2bf(__expf(v * rowf));
                } else {
                    ((float*)Cv)[(long)blockIdx.z * sC + r * ldc + c] = v * rowf;
                }
            }
        }
    }
}

__global__ __launch_bounds__(512, 4) void gemm8_qkv(const unsigned short* __restrict__ A,
                                                    const unsigned short* __restrict__ B,
                                                    void* __restrict__ Cv,
                                                    int K, int lda, int ldb, int ldc,
                                                    long sA, long sB, long sC) {
    gemm8_body<0>(A, B, Cv, nullptr, K, lda, ldb, ldc, sA, sB, sC, 0L, 1.0f);
}

__global__ __launch_bounds__(512, 4) void gemm8_scores(const unsigned short* __restrict__ A,
                                                       const unsigned short* __restrict__ B,
                                                       void* __restrict__ Cv,
                                                       const float* __restrict__ keep,
                                                       int K, int lda, int ldb, int ldc,
                                                       long sA, long sB, long sC, long sAux,
                                                       float scale) {
    gemm8_body<1>(A, B, Cv, keep, K, lda, ldb, ldc, sA, sB, sC, sAux, scale);
}

__global__ __launch_bounds__(512, 4) void gemm8_pv(const unsigned short* __restrict__ A,
                                                   const unsigned short* __restrict__ B,
                                                   void* __restrict__ Cv,
                                                   const float* __restrict__ invsum,
                                                   int K, int lda, int ldb, int ldc,
                                                   long sA, long sB, long sC, long sAux) {
    gemm8_body<2>(A, B, Cv, invsum, K, lda, ldb, ldc, sA, sB, sC, sAux, 1.0f);
}

// ---------------------------------------------------------------------------
__global__ __launch_bounds__(256) void rowsum_inv(const unsigned short* __restrict__ P,
                                                  float* __restrict__ inv, long strideP) {
    const int tid = threadIdx.x;
    const long row = blockIdx.x;
    short8 v = ((const short8*)(P + row * strideP))[tid];
    float s = 0.0f;
#pragma unroll
    for (int i = 0; i < 8; i++) s += bf2f((unsigned short)v[i]);
#pragma unroll
    for (int i = 1; i < 64; i <<= 1) s += __shfl_xor(s, i);
    __shared__ float ss[4];
    if ((tid & 63) == 0) ss[tid >> 6] = s;
    __syncthreads();
    if (tid == 0) {
        float t = (ss[0] + ss[1]) + (ss[2] + ss[3]);
        inv[row] = 1.0f / t;
    }
}

// ---------------------------------------------------------------------------
extern "C" void kernel_launch(void* const* d_in, const int* in_sizes, int n_in,
                              void* d_out, int out_size, void* d_ws, size_t ws_size,
                              hipStream_t stream) {
    const float* x  = (const float*)d_in[0];
    const void*  mask = d_in[1];
    const float* qw = (const float*)d_in[2];
    const float* kw = (const float*)d_in[3];
    const float* vw = (const float*)d_in[4];
    float* out = (float*)d_out;

    constexpr int B = 4, S = 2048, D = 1024;
    constexpr long BS  = (long)B * S;      // 8192
    constexpr long BSD = BS * D;           // 8388608

    char* w = (char*)d_ws;
    auto alloc = [&](size_t bytes) {
        char* p = w;
        w += (bytes + 255) & ~(size_t)255;
        return p;
    };
    int*            flag    = (int*)alloc(256);
    float*          keep    = (float*)alloc(BS * 4);
    float*          invsum  = (float*)alloc(BS * 4);
    unsigned short* xb      = (unsigned short*)alloc((size_t)BSD * 2);
    unsigned short* wT      = (unsigned short*)alloc((size_t)3 * D * D * 2);
    unsigned short* qkv     = (unsigned short*)alloc((size_t)3 * BSD * 2);
    unsigned short* Qb = qkv;
    unsigned short* Kb = qkv + BSD;
    unsigned short* Vb = qkv + 2 * BSD;
    unsigned short* Vt      = (unsigned short*)alloc((size_t)BSD * 2);

    size_t base_used = (size_t)(w - (char*)d_ws);
    size_t pB = (size_t)B * S * S * 2;  // 32 MiB unnormalized P (bf16)
    bool batched = ws_size >= base_used + pB + 1024;

    unsigned short* P;
    if (batched) {
        P = (unsigned short*)alloc(pB);
    } else {
        P = (unsigned short*)alloc((size_t)S * S * 2);
    }

    const float scale = 0.03125f;  // 1/sqrt(1024), exact

    mask_detect<<<1, 256, 0, stream>>>((const unsigned char*)mask, flag);
    mask_expand<<<(int)(BS / 256), 256, 0, stream>>>(mask, flag, keep, (int)BS);
    convert_f32_bf16<<<(int)(BSD / 1024), 256, 0, stream>>>(x, xb, BSD / 4);
    transpose_w_kernel<<<dim3(32, 32, 3), dim3(32, 8), 0, stream>>>(qw, kw, vw, wT);

    // Q,K,V projections: 64x4x3 = 768 blocks, 2 blocks/CU -> balanced 3/CU
    gemm8_qkv<<<dim3(64, 4, 3), 512, 0, stream>>>(xb, wT, qkv,
                                                  1024, 1024, 1024, 1024,
                                                  0L, (long)D * D, BSD);

    // V transpose: Vt[b][d][s]
    transpose_bf16<<<dim3(D / 32, S / 32, B), dim3(32, 8), 0, stream>>>(Vb, Vt, S, D,
                                                                        (long)S * D, (long)S * D);

    if (batched) {
        // P = exp(QK^T * scale * keep) unnormalized, bf16  (512 blocks = one 2/CU round)
        gemm8_scores<<<dim3(16, 8, B), 512, 0, stream>>>(Qb, Kb, P, keep,
                                                         1024, 1024, 1024, 2048,
                                                         (long)S * D, (long)S * D, (long)S * S, (long)S, scale);
        rowsum_inv<<<(int)BS, 256, 0, stream>>>(P, invsum, 2048);
        // out = (P * invsum[row]) . V   (256 blocks -> full CU coverage)
        gemm8_pv<<<dim3(16, 4, B), 512, 0, stream>>>(P, Vt, out, invsum,
                                                     2048, 2048, 2048, 1024,
                                                     (long)S * S, (long)D * S, (long)S * D, (long)S);
    } else {
        for (int b = 0; b < B; b++) {
            gemm8_scores<<<dim3(16, 8, 1), 512, 0, stream>>>(Qb + (long)b * S * D, Kb + (long)b * S * D,
                                                             P, keep + (long)b * S,
                                                             1024, 1024, 1024, 2048,
                                                             0L, 0L, 0L, 0L, scale);
            rowsum_inv<<<S, 256, 0, stream>>>(P, invsum + (long)b * S, 2048);
            gemm8_pv<<<dim3(16, 4, 1), 512, 0, stream>>>(P, Vt + (long)b * D * S, out + (long)b * S * D,
                                                         invsum + (long)b * S,
                                                         2048, 2048, 2048, 1024,
                                                         0L, 0L, 0L, 0L);
        }
    }
}